// Round 3
// baseline (3101.478 us; speedup 1.0000x reference)
//
#include <hip/hip_runtime.h>
#include <hip/hip_bf16.h>

// RadarTpaLSTM: 3-layer LSTM (B=1024,T=64,HD=512) + conv-attention head.
// Round 3: FP32 I/O (per reference dtypes / harness contract). Rounds 1-2 NaN
// root cause: inputs are fp32, were read as bf16 (random NaN bit patterns).
// Structure: diagonal-wavefront LSTM, 66 stage launches, stage s runs cells
// (l, t=s-l). 128x128 MFMA tiles (16x16x32 bf16), fp32->bf16 conversion at
// LDS staging, in-register gate nonlinearity, fp32 c state, bf16 h hand-off,
// fp32 epilogue, fp32 output.

typedef short v8s __attribute__((ext_vector_type(8)));
typedef float v4f __attribute__((ext_vector_type(4)));
typedef __hip_bfloat16 bf16;

#define B_   1024
#define T_   64
#define D_   512
#define HD_  512
#define LDA_ 72     // padded LDS row stride (ushort elems)

__device__ __forceinline__ float sigm(float v) { return 1.0f / (1.0f + __expf(-v)); }
__device__ __forceinline__ float tanh_(float v) { return 2.0f / (1.0f + __expf(-2.0f * v)) - 1.0f; }
__device__ __forceinline__ float b2f(bf16 v) { return __bfloat162float(v); }

// load 8 fp32, round to bf16, store 16B to LDS
__device__ __forceinline__ void cvt_store8(ushort* dst, const float* src) {
  float4 a = *(const float4*)src;
  float4 b = *(const float4*)(src + 4);
  bf16 h[8] = {__float2bfloat16(a.x), __float2bfloat16(a.y),
               __float2bfloat16(a.z), __float2bfloat16(a.w),
               __float2bfloat16(b.x), __float2bfloat16(b.y),
               __float2bfloat16(b.z), __float2bfloat16(b.w)};
  *(uint4*)dst = *(const uint4*)h;
}

// ---------------- workspace layout (total 75.51 MiB) ----------------
constexpr size_t SZ_YS = (size_t)T_ * B_ * HD_ * 2;     // bf16 [T][B][HD] layer-2 h
constexpr size_t SZ_HB = (size_t)2 * 2 * B_ * HD_ * 2;  // h layers 0/1, dbuf, bf16
constexpr size_t SZ_CB = (size_t)3 * B_ * HD_ * 4;      // c fp32, 3 layers
constexpr size_t SZ_ZP = (size_t)B_ * HD_ * 2;          // zero page (bf16)
constexpr size_t SZ_WV = (size_t)B_ * 64 * 4;           // w = htt@lin1^T fp32
constexpr size_t SZ_VB = (size_t)B_ * 64 * 4;           // v accumulator fp32
constexpr size_t O_YS = 0;
constexpr size_t O_HB = O_YS + SZ_YS;
constexpr size_t O_CB = O_HB + SZ_HB;
constexpr size_t O_ZP = O_CB + SZ_CB;
constexpr size_t O_WV = O_ZP + SZ_ZP;
constexpr size_t O_VB = O_WV + SZ_WV;

// ---------------- LSTM stage kernel ----------------
// Block: 256 thr, tile 128(batch) x 128(gate-major cols = 4 gates x 32 hidden),
// K = 1024 (input 512 + h-prev 512) in 16 chunks of 64.
__global__ __launch_bounds__(256) void lstm_stage(
    const float* __restrict__ x, const float* __restrict__ Wih,
    const float* __restrict__ Whh, const float* __restrict__ bih,
    const float* __restrict__ bhh, bf16* __restrict__ ys,
    bf16* __restrict__ hbuf, float* __restrict__ cbuf,
    const bf16* __restrict__ zp, int s, int llo) {
  __shared__ ushort As[128 * LDA_];
  __shared__ ushort Bs[128 * LDA_];

  const int layer = llo + (blockIdx.x >> 7);
  const int tile = blockIdx.x & 127;
  const int t = s - layer;
  const int mt = tile >> 4, nt = tile & 15;   // 8 batch tiles x 16 col tiles
  const int b0 = mt << 7;
  const int p = s & 1;

  // h write target: layers 0/1 -> hbuf (buffer p); layer 2 -> ys[t]
  bf16* hw = (layer < 2) ? hbuf + ((size_t)p * 2 + layer) * (B_ * HD_)
                         : ys + (size_t)t * (B_ * HD_);
  // input-h source for layers 1/2 (layer-l-1 h at time t, written last stage)
  const bf16* srcA0h = (layer == 1)
      ? hbuf + ((size_t)(p ^ 1) * 2 + 0) * (B_ * HD_)
      : hbuf + ((size_t)(p ^ 1) * 2 + 1) * (B_ * HD_);
  // own h at t-1
  const bf16* srcA1;
  if (layer < 2) srcA1 = hbuf + ((size_t)(p ^ 1) * 2 + layer) * (B_ * HD_);
  else           srcA1 = (t == 0) ? zp : ys + (size_t)(t - 1) * (B_ * HD_);

  const int tid = threadIdx.x;
  const int lane = tid & 63, wv = tid >> 6;
  const int c = lane & 15, q = lane >> 4;

  v4f acc[2][8];
#pragma unroll
  for (int mi = 0; mi < 2; ++mi)
#pragma unroll
    for (int ni = 0; ni < 8; ++ni) acc[mi][ni] = v4f{0.f, 0.f, 0.f, 0.f};

  for (int ch = 0; ch < 16; ++ch) {
    const int kof = (ch & 7) * 64;
    // ---- stage B tile: rows r = col-in-tile, cols kof..kof+63 of W (fp32) --
    const float* Wsrc = (ch < 8) ? Wih : Whh;
#pragma unroll
    for (int ii = 0; ii < 4; ++ii) {
      int flat = tid + ii * 256;
      int r = flat >> 3, kp = flat & 7;
      int gt = r >> 5, jj = r & 31;  // gate-major: tile col r -> orig row
      size_t wrow = (size_t)layer * 2048 + (size_t)gt * 512 + nt * 32 + jj;
      cvt_store8(&Bs[r * LDA_ + kp * 8], Wsrc + wrow * 512 + kof + kp * 8);
    }
    // ---- stage A tile: rows = batch ----
    if (ch < 8 && layer == 0) {
#pragma unroll
      for (int ii = 0; ii < 4; ++ii) {
        int flat = tid + ii * 256;
        int r = flat >> 3, kp = flat & 7;
        cvt_store8(&As[r * LDA_ + kp * 8],
                   x + (size_t)(b0 + r) * (T_ * D_) + (size_t)t * D_ + kof + kp * 8);
      }
    } else {
      const bf16* sA = (ch < 8) ? srcA0h : srcA1;
#pragma unroll
      for (int ii = 0; ii < 4; ++ii) {
        int flat = tid + ii * 256;
        int r = flat >> 3, kp = flat & 7;
        *(uint4*)&As[r * LDA_ + kp * 8] =
            *(const uint4*)(sA + (size_t)(b0 + r) * HD_ + kof + kp * 8);
      }
    }
    __syncthreads();
#pragma unroll
    for (int kk = 0; kk < 2; ++kk) {
      v8s af[2], bfr[8];
#pragma unroll
      for (int mi = 0; mi < 2; ++mi)
        af[mi] = *(const v8s*)&As[(wv * 32 + mi * 16 + c) * LDA_ + kk * 32 + q * 8];
#pragma unroll
      for (int ni = 0; ni < 8; ++ni)
        bfr[ni] = *(const v8s*)&Bs[(ni * 16 + c) * LDA_ + kk * 32 + q * 8];
#pragma unroll
      for (int mi = 0; mi < 2; ++mi)
#pragma unroll
        for (int ni = 0; ni < 8; ++ni)
          acc[mi][ni] = __builtin_amdgcn_mfma_f32_16x16x32_bf16(af[mi], bfr[ni], acc[mi][ni], 0, 0, 0);
    }
    __syncthreads();
  }

  // In-register cell update. acc block ni = gate*2 + jk (gate order i,f,g,o).
  float* cl = cbuf + (size_t)layer * (B_ * HD_);
  const size_t bb = (size_t)layer * 2048;
#pragma unroll
  for (int mi = 0; mi < 2; ++mi) {
#pragma unroll
    for (int jk = 0; jk < 2; ++jk) {
      const int j = nt * 32 + jk * 16 + c;  // hidden index
      const float bi  = bih[bb + j]        + bhh[bb + j];
      const float bff = bih[bb + 512 + j]  + bhh[bb + 512 + j];
      const float bg  = bih[bb + 1024 + j] + bhh[bb + 1024 + j];
      const float bo  = bih[bb + 1536 + j] + bhh[bb + 1536 + j];
#pragma unroll
      for (int r = 0; r < 4; ++r) {
        const int row = wv * 32 + mi * 16 + q * 4 + r;
        const int b = b0 + row;
        float iv = acc[mi][0 + jk][r] + bi;
        float fv = acc[mi][2 + jk][r] + bff;
        float gv = acc[mi][4 + jk][r] + bg;
        float ov = acc[mi][6 + jk][r] + bo;
        size_t off = (size_t)b * HD_ + j;
        float cprev = cl[off];
        float cn = sigm(fv) * cprev + sigm(iv) * tanh_(gv);
        float hn = sigm(ov) * tanh_(cn);
        cl[off] = cn;
        hw[off] = __float2bfloat16(hn);
      }
    }
  }
}

// ---------------- epilogue: w = htt @ lin1^T + lin1b ----------------
__global__ __launch_bounds__(64) void k0_lin1(const bf16* __restrict__ ys,
                                              const float* __restrict__ lin1W,
                                              const float* __restrict__ lin1b,
                                              float* __restrict__ wv) {
  __shared__ float htt[HD_];
  const int b = blockIdx.x, tid = threadIdx.x;
  for (int i = tid; i < HD_; i += 64)
    htt[i] = b2f(ys[((size_t)(T_ - 1) * B_ + b) * HD_ + i]);
  __syncthreads();
  float a = lin1b[tid];
  const float* wr = lin1W + (size_t)tid * HD_;
  for (int k = 0; k < HD_; k += 4) {
    float4 w4 = *(const float4*)(wr + k);
    a += htt[k] * w4.x + htt[k + 1] * w4.y + htt[k + 2] * w4.z + htt[k + 3] * w4.w;
  }
  wv[(size_t)b * 64 + tid] = a;
}

// ---------------- epilogue: conv einsum + attention ----------------
// conv_vecs[b,p,q] = relu(bcf)[b, c=(p*64+q)>>9, f=(p*64+q)&511]; with
// p = c*8 + (f>>6), q = f&63. Block (b,fg): handles f in [fg*64, fg*64+64),
// all 64 c -> 64 p values; partial v via atomics. 64 thr = 1 wave, 8x8 tile.
__global__ __launch_bounds__(64) void k1_attn(const bf16* __restrict__ ys,
                                              const float* __restrict__ convW,
                                              const float* __restrict__ convb,
                                              const float* __restrict__ wv,
                                              float* __restrict__ vbuf) {
  __shared__ float Hs[63 * 64];
  __shared__ float kT[63 * 64];
  __shared__ float wsh[64];
  __shared__ float cbs[64];
  const int b = blockIdx.x >> 3, fg = blockIdx.x & 7, f0 = fg << 6;
  const int tid = threadIdx.x;
  for (int idx = tid; idx < 63 * 64; idx += 64) {
    int t = idx >> 6, n = idx & 63;
    Hs[idx] = fmaxf(b2f(ys[((size_t)t * B_ + b) * HD_ + f0 + n]), 0.f);  // relu(H)
    kT[idx] = convW[n * 63 + t];  // kT[t][c]
  }
  wsh[tid] = wv[(size_t)b * 64 + tid];
  cbs[tid] = convb[tid];
  __syncthreads();

  const int ci = tid >> 3, fi = tid & 7;
  float acc[8][8];
#pragma unroll
  for (int i = 0; i < 8; ++i)
#pragma unroll
    for (int j = 0; j < 8; ++j) acc[i][j] = 0.f;

  for (int t = 0; t < 63; ++t) {
    float4 a0 = *(const float4*)&kT[t * 64 + ci * 8];
    float4 a1 = *(const float4*)&kT[t * 64 + ci * 8 + 4];
    float4 h0 = *(const float4*)&Hs[t * 64 + fi * 8];
    float4 h1 = *(const float4*)&Hs[t * 64 + fi * 8 + 4];
    float av[8] = {a0.x, a0.y, a0.z, a0.w, a1.x, a1.y, a1.z, a1.w};
    float hv[8] = {h0.x, h0.y, h0.z, h0.w, h1.x, h1.y, h1.z, h1.w};
#pragma unroll
    for (int i = 0; i < 8; ++i)
#pragma unroll
      for (int j = 0; j < 8; ++j) acc[i][j] += av[i] * hv[j];
  }
  // conv_vecs = relu(bcf + conv_b[c]) in place
#pragma unroll
  for (int i = 0; i < 8; ++i)
#pragma unroll
    for (int j = 0; j < 8; ++j) acc[i][j] = fmaxf(acc[i][j] + cbs[ci * 8 + i], 0.f);

  float vp[8];
#pragma unroll
  for (int j = 0; j < 8; ++j) vp[j] = 0.f;
#pragma unroll
  for (int i = 0; i < 8; ++i) {
    float sp = 0.f;
#pragma unroll
    for (int j = 0; j < 8; ++j) sp += acc[i][j] * wsh[fi * 8 + j];
    sp += __shfl_xor(sp, 1); sp += __shfl_xor(sp, 2); sp += __shfl_xor(sp, 4);
    float al = sigm(sp);
#pragma unroll
    for (int j = 0; j < 8; ++j) vp[j] += al * acc[i][j];
  }
#pragma unroll
  for (int j = 0; j < 8; ++j) {
    vp[j] += __shfl_xor(vp[j], 8);
    vp[j] += __shfl_xor(vp[j], 16);
    vp[j] += __shfl_xor(vp[j], 32);
  }
  if (ci == 0)
#pragma unroll
    for (int j = 0; j < 8; ++j) atomicAdd(&vbuf[(size_t)b * 64 + fi * 8 + j], vp[j]);
}

// ---------------- epilogue: new_ht = [htt,v]@lin2^T; out = new_ht@outW^T ------
__global__ __launch_bounds__(256) void k3_out(const bf16* __restrict__ ys,
                                              const float* __restrict__ vbuf,
                                              const float* __restrict__ lin2W,
                                              const float* __restrict__ lin2b,
                                              const float* __restrict__ outW,
                                              const float* __restrict__ outb,
                                              float* __restrict__ out) {
  __shared__ float htt[HD_];
  __shared__ float vsh[64];
  __shared__ float red[4];
  const int b = blockIdx.x, tid = threadIdx.x;
  for (int i = tid; i < HD_; i += 256)
    htt[i] = b2f(ys[((size_t)(T_ - 1) * B_ + b) * HD_ + i]);
  if (tid < 64) vsh[tid] = vbuf[(size_t)b * 64 + tid];
  __syncthreads();
  float psum = 0.f;
#pragma unroll
  for (int jj = 0; jj < 2; ++jj) {
    int j = tid + jj * 256;
    float a = lin2b[j];
    const float* wr = lin2W + (size_t)j * 576;
    for (int k = 0; k < 512; k += 4) {
      float4 w4 = *(const float4*)(wr + k);
      a += htt[k] * w4.x + htt[k + 1] * w4.y + htt[k + 2] * w4.z + htt[k + 3] * w4.w;
    }
    for (int n = 0; n < 64; n += 4) {
      float4 w4 = *(const float4*)(wr + 512 + n);
      a += vsh[n] * w4.x + vsh[n + 1] * w4.y + vsh[n + 2] * w4.z + vsh[n + 3] * w4.w;
    }
    psum += a * outW[j];
  }
  for (int m = 1; m < 64; m <<= 1) psum += __shfl_xor(psum, m);
  if ((tid & 63) == 0) red[tid >> 6] = psum;
  __syncthreads();
  if (tid == 0)
    out[b] = red[0] + red[1] + red[2] + red[3] + outb[0];
}

// ---------------- launch ----------------
extern "C" void kernel_launch(void* const* d_in, const int* in_sizes, int n_in,
                              void* d_out, int out_size, void* d_ws, size_t ws_size,
                              hipStream_t stream) {
  const float* x     = (const float*)d_in[0];
  const float* Wih   = (const float*)d_in[1];
  const float* Whh   = (const float*)d_in[2];
  const float* bih   = (const float*)d_in[3];
  const float* bhh   = (const float*)d_in[4];
  const float* convW = (const float*)d_in[5];
  const float* convb = (const float*)d_in[6];
  const float* lin1W = (const float*)d_in[7];
  const float* lin1b = (const float*)d_in[8];
  const float* lin2W = (const float*)d_in[9];
  const float* lin2b = (const float*)d_in[10];
  const float* outW  = (const float*)d_in[11];
  const float* outb  = (const float*)d_in[12];

  char* ws = (char*)d_ws;
  bf16*  ys   = (bf16*)(ws + O_YS);
  bf16*  hbuf = (bf16*)(ws + O_HB);
  float* cbuf = (float*)(ws + O_CB);
  bf16*  zp   = (bf16*)(ws + O_ZP);
  float* wv   = (float*)(ws + O_WV);
  float* vbuf = (float*)(ws + O_VB);

  hipMemsetAsync(hbuf, 0, SZ_HB, stream);
  hipMemsetAsync(cbuf, 0, SZ_CB, stream);
  hipMemsetAsync((void*)zp, 0, SZ_ZP, stream);
  hipMemsetAsync(vbuf, 0, SZ_VB, stream);

  // diagonal wavefront: stage s runs cells (l, t=s-l) for active layers
  for (int s = 0; s < T_ + 3 - 1; ++s) {
    int llo = (s > T_ - 1) ? (s - (T_ - 1)) : 0;
    int lhi = (s < 2) ? s : 2;
    int cnt = lhi - llo + 1;
    lstm_stage<<<cnt * 128, 256, 0, stream>>>(x, Wih, Whh, bih, bhh, ys, hbuf,
                                              cbuf, zp, s, llo);
  }

  k0_lin1<<<B_, 64, 0, stream>>>(ys, lin1W, lin1b, wv);
  k1_attn<<<B_ * 8, 64, 0, stream>>>(ys, convW, convb, wv, vbuf);
  k3_out<<<B_, 256, 0, stream>>>(ys, vbuf, lin2W, lin2b, outW, outb, (float*)d_out);
}

// Round 4
// 2738.443 us; speedup vs baseline: 1.1326x; 1.1326x over previous
//
#include <hip/hip_runtime.h>
#include <hip/hip_bf16.h>

// RadarTpaLSTM: 3-layer LSTM (B=1024,T=64,HD=512) + conv-attention head.
// Round 4: throughput. Diagonal wavefront kept (66 stage launches).
//  - prep_w: weights -> fragment-ordered gate-interleaved bf16 Wbuf (12.6MB).
//  - lstm_stage: global_load_lds(16B) staging into fragment-ordered LDS,
//    m97-style 64x64 wave tiles (4x4 acc), conflict-free ds_read_b128.
//  - k1_attn: per-b 256-thread blocks, bf16 LDS, coalesced 1KB row loads.
// Fragment layout (single source of truth, used by prep_w AND lstm_stage):
//   B-tile (128 perm-cols x 64 k) per (layer,nt,ch): frag fb = nb*2+kk,
//   elem (fb, lane, j) = W[permcol = nt*128 + nb*16 + (lane&15)]
//                         [k = ch*64 + kk*32 + (lane>>4)*8 + j]
//   perm-col win = nb*16+c: half=nb>>2, gate=nb&3, j_hid = nt*32+half*16+c,
//   orig row = gate*512 + j_hid.  (gate order i,f,g,o)
//   A-tile (128 rows x 64 k): frag fa = mb*2+kk,
//   elem = A[row = b0 + mb*16 + (lane&15)][k = kof + kk*32 + (lane>>4)*8 + j]

typedef short v8s __attribute__((ext_vector_type(8)));
typedef float v4f __attribute__((ext_vector_type(4)));
typedef __hip_bfloat16 bf16;

#define B_   1024
#define T_   64
#define D_   512
#define HD_  512

__device__ __forceinline__ float sigm(float v) { return 1.0f / (1.0f + __expf(-v)); }
__device__ __forceinline__ float tanh_(float v) { return 2.0f / (1.0f + __expf(-2.0f * v)) - 1.0f; }
__device__ __forceinline__ float b2f(bf16 v) { return __bfloat162float(v); }
__device__ __forceinline__ float bu2f(ushort u) {
  union { unsigned i; float f; } x; x.i = ((unsigned)u) << 16; return x.f;
}

// load 8 fp32, round to bf16, store 16B
__device__ __forceinline__ void cvt_store8(ushort* dst, const float* src) {
  float4 a = *(const float4*)src;
  float4 b = *(const float4*)(src + 4);
  bf16 h[8] = {__float2bfloat16(a.x), __float2bfloat16(a.y),
               __float2bfloat16(a.z), __float2bfloat16(a.w),
               __float2bfloat16(b.x), __float2bfloat16(b.y),
               __float2bfloat16(b.z), __float2bfloat16(b.w)};
  *(uint4*)dst = *(const uint4*)h;
}

// async global->LDS, 16B per lane; lds base must be wave-uniform.
__device__ __forceinline__ void glds16(const bf16* g, ushort* l) {
  __builtin_amdgcn_global_load_lds(
      (const __attribute__((address_space(1))) void*)g,
      (__attribute__((address_space(3))) void*)l, 16, 0, 0);
}

// ---------------- workspace layout ----------------
constexpr size_t SZ_YS = (size_t)T_ * B_ * HD_ * 2;     // bf16 [T][B][HD] layer-2 h
constexpr size_t SZ_HB = (size_t)2 * 2 * B_ * HD_ * 2;  // h layers 0/1, dbuf, bf16
constexpr size_t SZ_CB = (size_t)3 * B_ * HD_ * 4;      // c fp32, 3 layers
constexpr size_t SZ_ZP = (size_t)B_ * HD_ * 2;          // zero page (bf16)
constexpr size_t SZ_WV = (size_t)B_ * 64 * 4;           // w = htt@lin1^T fp32
constexpr size_t SZ_VB = (size_t)B_ * 64 * 4;           // v accumulator fp32
constexpr size_t SZ_WB = (size_t)3 * 2048 * 1024 * 2;   // frag-ordered bf16 weights
constexpr size_t SZ_KT = (size_t)64 * 64 * 2;           // conv kernel transposed bf16
constexpr size_t O_YS = 0;
constexpr size_t O_HB = O_YS + SZ_YS;
constexpr size_t O_CB = O_HB + SZ_HB;
constexpr size_t O_ZP = O_CB + SZ_CB;
constexpr size_t O_WV = O_ZP + SZ_ZP;
constexpr size_t O_VB = O_WV + SZ_WV;
constexpr size_t O_WB = O_VB + SZ_VB;
constexpr size_t O_KT = O_WB + SZ_WB;

// ---------------- prep: weights -> fragment-ordered bf16 ----------------
__global__ __launch_bounds__(256) void prep_w(const float* __restrict__ Wih,
                                              const float* __restrict__ Whh,
                                              bf16* __restrict__ Wbuf) {
  int tf = blockIdx.x * 256 + threadIdx.x;  // [0, 786432), 8 elems each
  int group = tf >> 10;                     // (layer, nt, ch)
  int layer = group >> 8, rem = group & 255;
  int nt = rem >> 4, ch = rem & 15;
  int li = tf & 1023;
  int frag = li >> 6, lane = li & 63;
  int nb = frag >> 1, kk = frag & 1;
  int c = lane & 15, q = lane >> 4;
  int half = nb >> 2, gate = nb & 3;
  int j = nt * 32 + half * 16 + c;
  int R = gate * 512 + j;
  int k = (ch & 7) * 64 + kk * 32 + q * 8;
  const float* src = ((ch < 8) ? Wih : Whh) + ((size_t)layer * 2048 + R) * 512 + k;
  cvt_store8((ushort*)(Wbuf + (size_t)tf * 8), src);
}

// conv kernel transpose: kT[t][c] = convW[c][t], bf16
__global__ __launch_bounds__(256) void prep_kt(const float* __restrict__ convW,
                                               bf16* __restrict__ kT) {
  int idx = blockIdx.x * 256 + threadIdx.x;  // < 4096
  int t = idx >> 6, c = idx & 63;
  kT[idx] = __float2bfloat16(t < 63 ? convW[c * 63 + t] : 0.f);
}

// ---------------- LSTM stage kernel ----------------
// Block: 256 thr, tile 128(batch) x 128(perm cols). Wave w = (wm=w>>1, wn=w&1)
// computes 64x64: rows wm*64.., n-blocks wn*4.. (= gates 0..3 of half wn).
__global__ __launch_bounds__(256) void lstm_stage(
    const float* __restrict__ x, const bf16* __restrict__ Wbuf,
    const float* __restrict__ bih, const float* __restrict__ bhh,
    bf16* __restrict__ ys, bf16* __restrict__ hbuf, float* __restrict__ cbuf,
    const bf16* __restrict__ zp, int s, int llo) {
  __shared__ ushort As[8192];
  __shared__ ushort Bs[8192];

  const int layer = llo + (blockIdx.x >> 7);
  const int tile = blockIdx.x & 127;
  const int t = s - layer;
  const int mt = tile >> 4, nt = tile & 15;
  const int b0 = mt << 7;
  const int p = s & 1;

  bf16* hw = (layer < 2) ? hbuf + ((size_t)p * 2 + layer) * (B_ * HD_)
                         : ys + (size_t)t * (B_ * HD_);
  const bf16* srcA0h = hbuf + ((size_t)(p ^ 1) * 2 + (layer - 1)) * (B_ * HD_);
  const bf16* srcA1 = (layer < 2)
      ? hbuf + ((size_t)(p ^ 1) * 2 + layer) * (B_ * HD_)
      : ((t == 0) ? zp : ys + (size_t)(t - 1) * (B_ * HD_));
  const bf16* Wb = Wbuf + ((size_t)layer * 16 + nt) * 16 * 8192;

  const int tid = threadIdx.x, lane = tid & 63, w = tid >> 6;
  const int c = lane & 15, q = lane >> 4;
  const int wm = w >> 1, wn = w & 1;

  v4f acc[4][4];
#pragma unroll
  for (int mi = 0; mi < 4; ++mi)
#pragma unroll
    for (int ni = 0; ni < 4; ++ni) acc[mi][ni] = v4f{0.f, 0.f, 0.f, 0.f};

  for (int ch = 0; ch < 16; ++ch) {
    const int kof = (ch & 7) * 64;
    // --- B stage: 4 frags per wave from frag-ordered Wbuf (coalesced) ---
    const bf16* wsrc = Wb + (size_t)ch * 8192;
#pragma unroll
    for (int i = 0; i < 4; ++i) {
      int f = w * 4 + i;
      glds16(wsrc + f * 512 + lane * 8, &Bs[f * 512]);
    }
    // --- A stage ---
    if (ch < 8 && layer == 0) {
#pragma unroll
      for (int i = 0; i < 4; ++i) {
        int f = w * 4 + i, mb = f >> 1, kk = f & 1;
        const float* src = x + (size_t)(b0 + mb * 16 + c) * (T_ * D_) +
                           (size_t)t * D_ + kof + kk * 32 + q * 8;
        cvt_store8(&As[f * 512 + lane * 8], src);
      }
    } else {
      const bf16* sA = (ch < 8) ? srcA0h : srcA1;
#pragma unroll
      for (int i = 0; i < 4; ++i) {
        int f = w * 4 + i, mb = f >> 1, kk = f & 1;
        glds16(sA + (size_t)(b0 + mb * 16 + c) * HD_ + kof + kk * 32 + q * 8,
               &As[f * 512]);
      }
    }
    __syncthreads();
#pragma unroll
    for (int kk = 0; kk < 2; ++kk) {
      v8s af[4], bfr[4];
#pragma unroll
      for (int mi = 0; mi < 4; ++mi)
        af[mi] = *(const v8s*)&As[((wm * 4 + mi) * 2 + kk) * 512 + lane * 8];
#pragma unroll
      for (int ni = 0; ni < 4; ++ni)
        bfr[ni] = *(const v8s*)&Bs[((wn * 4 + ni) * 2 + kk) * 512 + lane * 8];
#pragma unroll
      for (int mi = 0; mi < 4; ++mi)
#pragma unroll
        for (int ni = 0; ni < 4; ++ni)
          acc[mi][ni] = __builtin_amdgcn_mfma_f32_16x16x32_bf16(af[mi], bfr[ni], acc[mi][ni], 0, 0, 0);
    }
    __syncthreads();
  }

  // ---- in-register cell update: thread owns gates i,f,g,o (ni=gate) at
  // hidden j = nt*32 + wn*16 + c, rows wm*64 + mi*16 + q*4 + r ----
  float* cl = cbuf + (size_t)layer * (B_ * HD_);
  const size_t bb = (size_t)layer * 2048;
  const int j = nt * 32 + wn * 16 + c;
  float bsum[4];
#pragma unroll
  for (int g4 = 0; g4 < 4; ++g4)
    bsum[g4] = bih[bb + g4 * 512 + j] + bhh[bb + g4 * 512 + j];
#pragma unroll
  for (int mi = 0; mi < 4; ++mi) {
#pragma unroll
    for (int r = 0; r < 4; ++r) {
      const int b = b0 + wm * 64 + mi * 16 + q * 4 + r;
      float iv = acc[mi][0][r] + bsum[0];
      float fv = acc[mi][1][r] + bsum[1];
      float gv = acc[mi][2][r] + bsum[2];
      float ov = acc[mi][3][r] + bsum[3];
      size_t off = (size_t)b * HD_ + j;
      float cprev = cl[off];
      float cn = sigm(fv) * cprev + sigm(iv) * tanh_(gv);
      float hn = sigm(ov) * tanh_(cn);
      cl[off] = cn;
      hw[off] = __float2bfloat16(hn);
    }
  }
}

// ---------------- epilogue: w = htt @ lin1^T + lin1b ----------------
__global__ __launch_bounds__(64) void k0_lin1(const bf16* __restrict__ ys,
                                              const float* __restrict__ lin1W,
                                              const float* __restrict__ lin1b,
                                              float* __restrict__ wv) {
  __shared__ float htt[HD_];
  const int b = blockIdx.x, tid = threadIdx.x;
  for (int i = tid; i < HD_; i += 64)
    htt[i] = b2f(ys[((size_t)(T_ - 1) * B_ + b) * HD_ + i]);
  __syncthreads();
  float a = lin1b[tid];
  const float* wr = lin1W + (size_t)tid * HD_;
  for (int k = 0; k < HD_; k += 4) {
    float4 w4 = *(const float4*)(wr + k);
    a += htt[k] * w4.x + htt[k + 1] * w4.y + htt[k + 2] * w4.z + htt[k + 3] * w4.w;
  }
  wv[(size_t)b * 64 + tid] = a;
}

// ---------------- epilogue: conv einsum + attention (per b) ----------------
// 256 thr / 4 waves; wave w handles fg = w*2+{0,1} (f0 = fg*64).
// Per (wave,fg): lane (ci=lane>>3, fi=lane&7) computes 8x8 (c x f) tile.
__global__ __launch_bounds__(256) void k1_attn(const bf16* __restrict__ ys,
                                               const bf16* __restrict__ kTb,
                                               const float* __restrict__ convb,
                                               const float* __restrict__ wv,
                                               float* __restrict__ vbuf) {
  __shared__ ushort HsL[63 * 512];   // relu(H[b]) bf16
  __shared__ ushort kTL[64 * 64];    // kT[t][c] bf16 (t=63 row zero)
  __shared__ float wsh[64];
  __shared__ float cbs[64];
  const int b = blockIdx.x;
  const int tid = threadIdx.x, lane = tid & 63, w = tid >> 6;

  for (int idx = tid; idx < 63 * 64; idx += 256) {  // 63 rows x 64 groups of 8
    int t = idx >> 6, c8 = idx & 63;
    v8s h = *(const v8s*)(ys + ((size_t)t * B_ + b) * HD_ + c8 * 8);
    v8s r;
#pragma unroll
    for (int e = 0; e < 8; ++e) r[e] = (h[e] & (short)0x8000) ? (short)0 : h[e];
    *(v8s*)&HsL[t * 512 + c8 * 8] = r;
  }
  for (int idx = tid; idx < 512; idx += 256)
    *(v8s*)&kTL[idx * 8] = *(const v8s*)(kTb + idx * 8);
  if (tid < 64) { wsh[tid] = wv[(size_t)b * 64 + tid]; cbs[tid] = convb[tid]; }
  __syncthreads();

  const int ci = lane >> 3, fi = lane & 7;
#pragma unroll
  for (int fgi = 0; fgi < 2; ++fgi) {
    const int fg = w * 2 + fgi, f0 = fg << 6;
    float acc[8][8];
#pragma unroll
    for (int i = 0; i < 8; ++i)
#pragma unroll
      for (int jx = 0; jx < 8; ++jx) acc[i][jx] = 0.f;
    for (int t = 0; t < 63; ++t) {
      v8s k8 = *(const v8s*)&kTL[t * 64 + ci * 8];
      v8s h8 = *(const v8s*)&HsL[t * 512 + f0 + fi * 8];
      float av[8], hv[8];
#pragma unroll
      for (int e = 0; e < 8; ++e) { av[e] = bu2f((ushort)k8[e]); hv[e] = bu2f((ushort)h8[e]); }
#pragma unroll
      for (int i = 0; i < 8; ++i)
#pragma unroll
        for (int jx = 0; jx < 8; ++jx) acc[i][jx] += av[i] * hv[jx];
    }
#pragma unroll
    for (int i = 0; i < 8; ++i)
#pragma unroll
      for (int jx = 0; jx < 8; ++jx)
        acc[i][jx] = fmaxf(acc[i][jx] + cbs[ci * 8 + i], 0.f);

    float vp[8];
#pragma unroll
    for (int jx = 0; jx < 8; ++jx) vp[jx] = 0.f;
#pragma unroll
    for (int i = 0; i < 8; ++i) {
      float sp = 0.f;
#pragma unroll
      for (int jx = 0; jx < 8; ++jx) sp += acc[i][jx] * wsh[fi * 8 + jx];
      sp += __shfl_xor(sp, 1); sp += __shfl_xor(sp, 2); sp += __shfl_xor(sp, 4);
      float al = sigm(sp);
#pragma unroll
      for (int jx = 0; jx < 8; ++jx) vp[jx] += al * acc[i][jx];
    }
#pragma unroll
    for (int jx = 0; jx < 8; ++jx) {
      vp[jx] += __shfl_xor(vp[jx], 8);
      vp[jx] += __shfl_xor(vp[jx], 16);
      vp[jx] += __shfl_xor(vp[jx], 32);
    }
    if (ci == 0)
#pragma unroll
      for (int jx = 0; jx < 8; ++jx)
        atomicAdd(&vbuf[(size_t)b * 64 + fi * 8 + jx], vp[jx]);
  }
}

// ---------------- epilogue: new_ht = [htt,v]@lin2^T; out = new_ht@outW^T ------
__global__ __launch_bounds__(256) void k3_out(const bf16* __restrict__ ys,
                                              const float* __restrict__ vbuf,
                                              const float* __restrict__ lin2W,
                                              const float* __restrict__ lin2b,
                                              const float* __restrict__ outW,
                                              const float* __restrict__ outb,
                                              float* __restrict__ out) {
  __shared__ float htt[HD_];
  __shared__ float vsh[64];
  __shared__ float red[4];
  const int b = blockIdx.x, tid = threadIdx.x;
  for (int i = tid; i < HD_; i += 256)
    htt[i] = b2f(ys[((size_t)(T_ - 1) * B_ + b) * HD_ + i]);
  if (tid < 64) vsh[tid] = vbuf[(size_t)b * 64 + tid];
  __syncthreads();
  float psum = 0.f;
#pragma unroll
  for (int jj = 0; jj < 2; ++jj) {
    int j = tid + jj * 256;
    float a = lin2b[j];
    const float* wr = lin2W + (size_t)j * 576;
    for (int k = 0; k < 512; k += 4) {
      float4 w4 = *(const float4*)(wr + k);
      a += htt[k] * w4.x + htt[k + 1] * w4.y + htt[k + 2] * w4.z + htt[k + 3] * w4.w;
    }
    for (int n = 0; n < 64; n += 4) {
      float4 w4 = *(const float4*)(wr + 512 + n);
      a += vsh[n] * w4.x + vsh[n + 1] * w4.y + vsh[n + 2] * w4.z + vsh[n + 3] * w4.w;
    }
    psum += a * outW[j];
  }
  for (int m = 1; m < 64; m <<= 1) psum += __shfl_xor(psum, m);
  if ((tid & 63) == 0) red[tid >> 6] = psum;
  __syncthreads();
  if (tid == 0)
    out[b] = red[0] + red[1] + red[2] + red[3] + outb[0];
}

// ---------------- launch ----------------
extern "C" void kernel_launch(void* const* d_in, const int* in_sizes, int n_in,
                              void* d_out, int out_size, void* d_ws, size_t ws_size,
                              hipStream_t stream) {
  const float* x     = (const float*)d_in[0];
  const float* Wih   = (const float*)d_in[1];
  const float* Whh   = (const float*)d_in[2];
  const float* bih   = (const float*)d_in[3];
  const float* bhh   = (const float*)d_in[4];
  const float* convW = (const float*)d_in[5];
  const float* convb = (const float*)d_in[6];
  const float* lin1W = (const float*)d_in[7];
  const float* lin1b = (const float*)d_in[8];
  const float* lin2W = (const float*)d_in[9];
  const float* lin2b = (const float*)d_in[10];
  const float* outW  = (const float*)d_in[11];
  const float* outb  = (const float*)d_in[12];

  char* ws = (char*)d_ws;
  bf16*  ys   = (bf16*)(ws + O_YS);
  bf16*  hbuf = (bf16*)(ws + O_HB);
  float* cbuf = (float*)(ws + O_CB);
  bf16*  zp   = (bf16*)(ws + O_ZP);
  float* wv   = (float*)(ws + O_WV);
  float* vbuf = (float*)(ws + O_VB);
  bf16*  Wbuf = (bf16*)(ws + O_WB);
  bf16*  kTb  = (bf16*)(ws + O_KT);

  hipMemsetAsync(hbuf, 0, SZ_HB, stream);
  hipMemsetAsync(cbuf, 0, SZ_CB, stream);
  hipMemsetAsync((void*)zp, 0, SZ_ZP, stream);
  hipMemsetAsync(vbuf, 0, SZ_VB, stream);

  prep_w<<<3072, 256, 0, stream>>>(Wih, Whh, Wbuf);
  prep_kt<<<16, 256, 0, stream>>>(convW, kTb);

  // diagonal wavefront: stage s runs cells (l, t=s-l) for active layers
  for (int s = 0; s < T_ + 3 - 1; ++s) {
    int llo = (s > T_ - 1) ? (s - (T_ - 1)) : 0;
    int lhi = (s < 2) ? s : 2;
    int cnt = lhi - llo + 1;
    lstm_stage<<<cnt * 128, 256, 0, stream>>>(x, Wbuf, bih, bhh, ys, hbuf,
                                              cbuf, zp, s, llo);
  }

  k0_lin1<<<B_, 64, 0, stream>>>(ys, lin1W, lin1b, wv);
  k1_attn<<<B_, 256, 0, stream>>>(ys, kTb, convb, wv, vbuf);
  k3_out<<<B_, 256, 0, stream>>>(ys, vbuf, lin2W, lin2b, outW, outb, (float*)d_out);
}